// Round 3
// baseline (117.363 us; speedup 1.0000x reference)
//
#include <hip/hip_runtime.h>
#include <hip/hip_cooperative_groups.h>
#include <math.h>

namespace cg = cooperative_groups;

// Problem: x[B=32][N=2048][K=8], W[N][C=32][J=16][K=8], R[N][C]
// out[b][c][j] = squash_j( sum_n softmax_n(R)[n,c] * sum_k W[n,c,j,k]*x[b,n,k] )

#define NN 2048
#define CC 32

__device__ __forceinline__ void g2l16(const float* g, float* l) {
  __builtin_amdgcn_global_load_lds((const __attribute__((address_space(1))) void*)g,
                                   (__attribute__((address_space(3))) void*)l, 16, 0, 0);
}

// Single cooperative kernel: 256 blocks x 512 threads, 96KB dynamic LDS.
// block: cg = bid&3 (8 c's), chunk = bid>>2 (32 n's). 8 waves; wave ws computes
// n = n0 + s*8 + ws for slab s in 0..3. lane: j = lane&15, bo = lane>>4.
// acc[bi 8][ci 8]; b = bo*8+bi, c = cg*8+ci.
// LDS: ldsW[2][8192]f (double-buffered 8-n W slabs, granule-swizzled),
//      ldsX[2048]f (all 32 n of x: [n][bi 8][bo 4][k 8]).
__global__ void __launch_bounds__(512) caps_fused(const float* __restrict__ x,
                                                  const float* __restrict__ W,
                                                  const float* __restrict__ R,
                                                  float* __restrict__ P,
                                                  float* __restrict__ out) {
  const int bid = blockIdx.x;
  const int cg_ = bid & 3;
  const int chunk = bid >> 2;
  const int n0 = chunk * 32;
  const int tid = threadIdx.x;
  const int ws = tid >> 6;
  const int lane = tid & 63;
  const int j = lane & 15;
  const int bo = lane >> 4;

  extern __shared__ float smem[];
  float* ldsW = smem;           // [2][8192]
  float* ldsX = smem + 16384;   // [2048 granules * 4] = 8192 floats
  float* red8 = smem + 8192;    // 64 floats, inside ldsW[1] (staged only later)

  // ---- prologue: issue async staging of W slab 0 + all x (64KB total) ----
#pragma unroll
  for (int it = 0; it < 4; ++it) {
    int G = it * 512 + tid;
    int q = G & 255, nl = G >> 8;
    int qs = q ^ ((q >> 3) & 1);
    g2l16(W + (size_t)(n0 + nl) * 4096 + cg_ * 1024 + qs * 4,
          ldsW + (size_t)(it * 512 + ws * 64) * 4);
  }
#pragma unroll
  for (int it = 0; it < 4; ++it) {
    int G = it * 512 + tid;
    int nl = G >> 6, r = G & 63;
    int bi = r >> 3, bo2 = (r >> 1) & 3, h = r & 1;
    int b = bo2 * 8 + bi;
    g2l16(x + (size_t)b * (NN * 8) + (size_t)(n0 + nl) * 8 + h * 4,
          ldsX + (size_t)(it * 512 + ws * 64) * 4);
  }

  // ---- Phase 0 (overlaps staging): softmax denominators for this block's 8 c ----
  float se[8];
#pragma unroll
  for (int ci = 0; ci < 8; ++ci) se[ci] = 0.f;
#pragma unroll
  for (int i = 0; i < 4; ++i) {
    int n = i * 512 + tid;
    const float* rp = R + (size_t)n * CC + cg_ * 8;
    float4 a = *(const float4*)rp;
    float4 b = *(const float4*)(rp + 4);
    se[0] += expf(a.x); se[1] += expf(a.y); se[2] += expf(a.z); se[3] += expf(a.w);
    se[4] += expf(b.x); se[5] += expf(b.y); se[6] += expf(b.z); se[7] += expf(b.w);
  }
#pragma unroll
  for (int ci = 0; ci < 8; ++ci) {
    float v = se[ci];
#pragma unroll
    for (int d = 32; d >= 1; d >>= 1) v += __shfl_xor(v, d, 64);
    se[ci] = v;
  }
  if (lane == 0) {
#pragma unroll
    for (int ci = 0; ci < 8; ++ci) red8[ws * 8 + ci] = se[ci];
  }
  __syncthreads();  // drains prologue g2l16 too (vmcnt 0 at barrier)

  float inv8[8];
  {
    float t[8];
#pragma unroll
    for (int ci = 0; ci < 8; ++ci) t[ci] = 0.f;
#pragma unroll
    for (int w = 0; w < 8; ++w)
#pragma unroll
      for (int ci = 0; ci < 8; ++ci) t[ci] += red8[w * 8 + ci];
#pragma unroll
    for (int ci = 0; ci < 8; ++ci) inv8[ci] = 1.0f / t[ci];
  }
  __syncthreads();  // red8 reads done before slab-1 prefetch overwrites ldsW[1]

  // ---- Phase 1: main contraction over this chunk's 32 n ----
  float acc[8][8];
#pragma unroll
  for (int a = 0; a < 8; ++a)
#pragma unroll
    for (int b = 0; b < 8; ++b) acc[a][b] = 0.f;

  const int xw = (j >> 2) & 1;
  const int jo_lo = j * 8 + xw * 4;
  const int jo_hi = j * 8 + (xw ^ 1) * 4;

#pragma unroll 1
  for (int s = 0; s < 4; ++s) {
    const int cur = s & 1;
    if (s < 3) {
      const int nxt = cur ^ 1;
      const int sb = n0 + (s + 1) * 8;
#pragma unroll
      for (int it = 0; it < 4; ++it) {
        int G = it * 512 + tid;
        int q = G & 255, nl = G >> 8;
        int qs = q ^ ((q >> 3) & 1);
        g2l16(W + (size_t)(sb + nl) * 4096 + cg_ * 1024 + qs * 4,
              ldsW + (size_t)nxt * 8192 + (size_t)(it * 512 + ws * 64) * 4);
      }
    }
    const int n = n0 + s * 8 + ws;
    const float* Xb = ldsX + (size_t)(s * 8 + ws) * 256;
    const float* Wb = ldsW + (size_t)cur * 8192 + (size_t)ws * 1024;

    float xa[8][8];
#pragma unroll
    for (int bi = 0; bi < 8; ++bi) {
      float4 lo = *(const float4*)(Xb + bi * 32 + bo * 8);
      float4 hi = *(const float4*)(Xb + bi * 32 + bo * 8 + 4);
      xa[bi][0] = lo.x; xa[bi][1] = lo.y; xa[bi][2] = lo.z; xa[bi][3] = lo.w;
      xa[bi][4] = hi.x; xa[bi][5] = hi.y; xa[bi][6] = hi.z; xa[bi][7] = hi.w;
    }

    const float* rr = R + (size_t)n * CC + cg_ * 8;
    float rv[8];
#pragma unroll
    for (int ci = 0; ci < 8; ++ci) rv[ci] = expf(rr[ci]) * inv8[ci];

#pragma unroll
    for (int ci = 0; ci < 8; ++ci) {
      float4 wa = *(const float4*)(Wb + ci * 128 + jo_lo);
      float4 wb = *(const float4*)(Wb + ci * 128 + jo_hi);
      float rvv = rv[ci];
      float w0 = wa.x * rvv, w1 = wa.y * rvv, w2 = wa.z * rvv, w3 = wa.w * rvv;
      float w4 = wb.x * rvv, w5 = wb.y * rvv, w6 = wb.z * rvv, w7 = wb.w * rvv;
#pragma unroll
      for (int bi = 0; bi < 8; ++bi) {
        float a = acc[bi][ci];
        a = fmaf(w0, xa[bi][0], a);
        a = fmaf(w1, xa[bi][1], a);
        a = fmaf(w2, xa[bi][2], a);
        a = fmaf(w3, xa[bi][3], a);
        a = fmaf(w4, xa[bi][4], a);
        a = fmaf(w5, xa[bi][5], a);
        a = fmaf(w6, xa[bi][6], a);
        a = fmaf(w7, xa[bi][7], a);
        acc[bi][ci] = a;
      }
    }
    __syncthreads();
  }

  // ---- cross-wave tree reduction (reuse ldsW region) ----
  float* red = smem;
#pragma unroll
  for (int half = 4; half >= 1; half >>= 1) {
    if (ws >= half && ws < 2 * half) {
      float* dst = red + (size_t)(ws - half) * 4096;
#pragma unroll
      for (int bi = 0; bi < 8; ++bi)
#pragma unroll
        for (int ci = 0; ci < 8; ++ci)
          dst[(bi * 8 + ci) * 64 + lane] = acc[bi][ci];
    }
    __syncthreads();
    if (ws < half) {
      const float* srcp = red + (size_t)ws * 4096;
#pragma unroll
      for (int bi = 0; bi < 8; ++bi)
#pragma unroll
        for (int ci = 0; ci < 8; ++ci)
          acc[bi][ci] += srcp[(bi * 8 + ci) * 64 + lane];
    }
    __syncthreads();
  }

  if (ws == 0) {
    float* dst = P + (size_t)bid * 4096;
#pragma unroll
    for (int bi = 0; bi < 8; ++bi)
#pragma unroll
      for (int ci = 0; ci < 8; ++ci)
        dst[(bi * 8 + ci) * 64 + lane] = acc[bi][ci];
  }

  __threadfence();
  cg::this_grid().sync();

  // ---- Phase 2: cross-chunk reduce + squash (blocks 0..31) ----
  if (bid < 32) {
    const int g = bid * 512 + tid;  // b*512 + c*16 + j
    const int jj = g & 15;
    const int c = (g >> 4) & 31;
    const int b = g >> 9;
    const int bo2 = b >> 3, bi = b & 7;
    const int cgi = c >> 3, ci = c & 7;
    const int idx = (bi * 8 + ci) * 64 + (bo2 * 16 + jj);

    float s = 0.f;
#pragma unroll
    for (int ch = 0; ch < 64; ++ch)
      s += P[(size_t)(ch * 4 + cgi) * 4096 + idx];

    float sq = s * s;
    sq += __shfl_xor(sq, 8, 16);
    sq += __shfl_xor(sq, 4, 16);
    sq += __shfl_xor(sq, 2, 16);
    sq += __shfl_xor(sq, 1, 16);
    float ss = sq + 1e-7f;
    float scale = sqrtf(ss) / (1.0f + ss);
    out[g] = scale * s;
  }
}

extern "C" void kernel_launch(void* const* d_in, const int* in_sizes, int n_in,
                              void* d_out, int out_size, void* d_ws, size_t ws_size,
                              hipStream_t stream) {
  const float* x = (const float*)d_in[0];   // 32*2048*8
  const float* W = (const float*)d_in[1];   // 2048*32*16*8
  const float* R = (const float*)d_in[2];   // 2048*32
  float* out = (float*)d_out;               // 32*32*16
  float* P = (float*)d_ws;                  // 256*4096 floats (4 MB)

  hipFuncSetAttribute((const void*)caps_fused,
                      hipFuncAttributeMaxDynamicSharedMemorySize, 98304);

  void* args[] = {(void*)&x, (void*)&W, (void*)&R, (void*)&P, (void*)&out};
  hipLaunchCooperativeKernel((void*)caps_fused, dim3(256), dim3(512), args,
                             98304, stream);
}

// Round 4
// 65.907 us; speedup vs baseline: 1.7807x; 1.7807x over previous
//
#include <hip/hip_runtime.h>
#include <math.h>

// Problem: x[B=32][N=2048][K=8], W[N][C=32][J=16][K=8], R[N][C]
// out[b][c][j] = squash_j( sum_n softmax_n(R)[n,c] * sum_k W[n,c,j,k]*x[b,n,k] )

#define NN 2048
#define CC 32

__device__ __forceinline__ void g2l16(const float* g, float* l) {
  __builtin_amdgcn_global_load_lds((const __attribute__((address_space(1))) void*)g,
                                   (__attribute__((address_space(3))) void*)l, 16, 0, 0);
}

// Kernel 1: fused softmax-stats + contraction.
// grid 512 = 128 n-chunks x 4 c-groups; block 512 = 8 waves; 80KB LDS -> 2 blocks/CU.
// chunk = 16 n, slabs of 8 n, double-buffered. Wave ws computes n = n0 + s*8 + ws.
// lane: j = lane&15, bo = lane>>4; acc[bi 8][ci 8]; b = bo*8+bi, c = cg*8+ci.
// LDS: ldsW[2][8192]f (granule-swizzled W slabs), ldsX[16][256]f ([n][bi][bo][k]).
__global__ void __launch_bounds__(512, 4) caps_main(const float* __restrict__ x,
                                                    const float* __restrict__ W,
                                                    const float* __restrict__ R,
                                                    float* __restrict__ P) {
  const int bid = blockIdx.x;
  const int cg_ = bid & 3;
  const int chunk = bid >> 2;
  const int n0 = chunk * 16;
  const int tid = threadIdx.x;
  const int ws = tid >> 6;
  const int lane = tid & 63;
  const int j = lane & 15;
  const int bo = lane >> 4;

  extern __shared__ float smem[];
  float* ldsW = smem;           // [2][8192] floats (64KB)
  float* ldsX = smem + 16384;   // [16][256] floats (16KB)
  float* red8 = smem + 8192;    // 64 floats inside ldsW[1] (consumed before slab-1 prefetch)

  // ---- prologue: async stage W slab 0 (32KB) + all x (16KB) ----
#pragma unroll
  for (int it = 0; it < 4; ++it) {
    int G = it * 512 + tid;
    int q = G & 255, nl = G >> 8;
    int qs = q ^ ((q >> 3) & 1);
    g2l16(W + (size_t)(n0 + nl) * 4096 + cg_ * 1024 + qs * 4,
          ldsW + (size_t)(it * 512 + ws * 64) * 4);
  }
#pragma unroll
  for (int it = 0; it < 2; ++it) {
    int G = it * 512 + tid;
    int nl = G >> 6, r = G & 63;
    int bi = r >> 3, bo2 = (r >> 1) & 3, h = r & 1;
    int b = bo2 * 8 + bi;
    g2l16(x + (size_t)b * (NN * 8) + (size_t)(n0 + nl) * 8 + h * 4,
          ldsX + (size_t)(it * 512 + ws * 64) * 4);
  }

  // ---- softmax denominators for this block's 8 c (overlaps staging) ----
  float se[8];
#pragma unroll
  for (int ci = 0; ci < 8; ++ci) se[ci] = 0.f;
#pragma unroll
  for (int i = 0; i < 4; ++i) {
    int n = i * 512 + tid;
    const float* rp = R + (size_t)n * CC + cg_ * 8;
    float4 a = *(const float4*)rp;
    float4 b = *(const float4*)(rp + 4);
    se[0] += expf(a.x); se[1] += expf(a.y); se[2] += expf(a.z); se[3] += expf(a.w);
    se[4] += expf(b.x); se[5] += expf(b.y); se[6] += expf(b.z); se[7] += expf(b.w);
  }
#pragma unroll
  for (int ci = 0; ci < 8; ++ci) {
    float v = se[ci];
#pragma unroll
    for (int d = 32; d >= 1; d >>= 1) v += __shfl_xor(v, d, 64);
    se[ci] = v;
  }
  if (lane == 0) {
#pragma unroll
    for (int ci = 0; ci < 8; ++ci) red8[ws * 8 + ci] = se[ci];
  }
  __syncthreads();  // also drains prologue g2l16

  float inv8[8];
  {
    float t[8];
#pragma unroll
    for (int ci = 0; ci < 8; ++ci) t[ci] = 0.f;
#pragma unroll
    for (int w = 0; w < 8; ++w)
#pragma unroll
      for (int ci = 0; ci < 8; ++ci) t[ci] += red8[w * 8 + ci];
#pragma unroll
    for (int ci = 0; ci < 8; ++ci) inv8[ci] = 1.0f / t[ci];
  }
  __syncthreads();  // red8 consumed before slab-1 prefetch may overwrite it

  // ---- main contraction: 2 slabs of 8 n, double-buffered ----
  float acc[8][8];
#pragma unroll
  for (int a = 0; a < 8; ++a)
#pragma unroll
    for (int b = 0; b < 8; ++b) acc[a][b] = 0.f;

  const int xw = (j >> 2) & 1;
  const int jo_lo = j * 8 + xw * 4;
  const int jo_hi = j * 8 + (xw ^ 1) * 4;

#pragma unroll 1
  for (int s = 0; s < 2; ++s) {
    const int cur = s & 1;
    if (s < 1) {
      const int sb = n0 + 8;
#pragma unroll
      for (int it = 0; it < 4; ++it) {
        int G = it * 512 + tid;
        int q = G & 255, nl = G >> 8;
        int qs = q ^ ((q >> 3) & 1);
        g2l16(W + (size_t)(sb + nl) * 4096 + cg_ * 1024 + qs * 4,
              ldsW + 8192 + (size_t)(it * 512 + ws * 64) * 4);
      }
    }
    const int n = n0 + s * 8 + ws;
    const float* Xb = ldsX + (size_t)(s * 8 + ws) * 256;
    const float* Wb = ldsW + (size_t)cur * 8192 + (size_t)ws * 1024;

    float xa[8][8];
#pragma unroll
    for (int bi = 0; bi < 8; ++bi) {
      float4 lo = *(const float4*)(Xb + bi * 32 + bo * 8);
      float4 hi = *(const float4*)(Xb + bi * 32 + bo * 8 + 4);
      xa[bi][0] = lo.x; xa[bi][1] = lo.y; xa[bi][2] = lo.z; xa[bi][3] = lo.w;
      xa[bi][4] = hi.x; xa[bi][5] = hi.y; xa[bi][6] = hi.z; xa[bi][7] = hi.w;
    }

    const float* rr = R + (size_t)n * CC + cg_ * 8;
    float rv[8];
#pragma unroll
    for (int ci = 0; ci < 8; ++ci) rv[ci] = expf(rr[ci]) * inv8[ci];

#pragma unroll
    for (int ci = 0; ci < 8; ++ci) {
      float4 wa = *(const float4*)(Wb + ci * 128 + jo_lo);
      float4 wb = *(const float4*)(Wb + ci * 128 + jo_hi);
      float rvv = rv[ci];
      float w0 = wa.x * rvv, w1 = wa.y * rvv, w2 = wa.z * rvv, w3 = wa.w * rvv;
      float w4 = wb.x * rvv, w5 = wb.y * rvv, w6 = wb.z * rvv, w7 = wb.w * rvv;
#pragma unroll
      for (int bi = 0; bi < 8; ++bi) {
        float a = acc[bi][ci];
        a = fmaf(w0, xa[bi][0], a);
        a = fmaf(w1, xa[bi][1], a);
        a = fmaf(w2, xa[bi][2], a);
        a = fmaf(w3, xa[bi][3], a);
        a = fmaf(w4, xa[bi][4], a);
        a = fmaf(w5, xa[bi][5], a);
        a = fmaf(w6, xa[bi][6], a);
        a = fmaf(w7, xa[bi][7], a);
        acc[bi][ci] = a;
      }
    }
    __syncthreads();
  }

  // ---- cross-wave tree reduction (reuse ldsW as 4 regions x 4096 floats) ----
  float* red = smem;
#pragma unroll
  for (int half = 4; half >= 1; half >>= 1) {
    if (ws >= half && ws < 2 * half) {
      float* dst = red + (size_t)(ws - half) * 4096;
#pragma unroll
      for (int bi = 0; bi < 8; ++bi)
#pragma unroll
        for (int ci = 0; ci < 8; ++ci)
          dst[(bi * 8 + ci) * 64 + lane] = acc[bi][ci];
    }
    __syncthreads();
    if (ws < half) {
      const float* srcp = red + (size_t)ws * 4096;
#pragma unroll
      for (int bi = 0; bi < 8; ++bi)
#pragma unroll
        for (int ci = 0; ci < 8; ++ci)
          acc[bi][ci] += srcp[(bi * 8 + ci) * 64 + lane];
    }
    __syncthreads();
  }

  if (ws == 0) {
    float* dst = P + (size_t)bid * 4096;
#pragma unroll
    for (int bi = 0; bi < 8; ++bi)
#pragma unroll
      for (int ci = 0; ci < 8; ++ci)
        dst[(bi * 8 + ci) * 64 + lane] = acc[bi][ci];
  }
}

// Kernel 2: cross-chunk reduce + squash. 64 blocks x 256 threads.
__global__ void caps_reduce(const float* __restrict__ P, float* __restrict__ out) {
  const int g = blockIdx.x * 256 + threadIdx.x;  // b*512 + c*16 + j
  const int j = g & 15;
  const int c = (g >> 4) & 31;
  const int b = g >> 9;
  const int bo = b >> 3, bi = b & 7;
  const int cgi = c >> 3, ci = c & 7;
  const int idx = (bi * 8 + ci) * 64 + (bo * 16 + j);

  float s = 0.f;
#pragma unroll 32
  for (int ch = 0; ch < 128; ++ch) {
    s += P[(size_t)(ch * 4 + cgi) * 4096 + idx];
  }
  float sq = s * s;
  sq += __shfl_xor(sq, 8, 16);
  sq += __shfl_xor(sq, 4, 16);
  sq += __shfl_xor(sq, 2, 16);
  sq += __shfl_xor(sq, 1, 16);
  float ss = sq + 1e-7f;
  float scale = sqrtf(ss) / (1.0f + ss);
  out[g] = scale * s;
}

extern "C" void kernel_launch(void* const* d_in, const int* in_sizes, int n_in,
                              void* d_out, int out_size, void* d_ws, size_t ws_size,
                              hipStream_t stream) {
  const float* x = (const float*)d_in[0];   // 32*2048*8
  const float* W = (const float*)d_in[1];   // 2048*32*16*8
  const float* R = (const float*)d_in[2];   // 2048*32
  float* out = (float*)d_out;               // 32*32*16
  float* P = (float*)d_ws;                  // 512*4096 floats (8 MB)

  hipFuncSetAttribute((const void*)caps_main,
                      hipFuncAttributeMaxDynamicSharedMemorySize, 81920);

  caps_main<<<512, 512, 81920, stream>>>(x, W, R, P);
  caps_reduce<<<64, 256, 0, stream>>>(P, out);
}

// Round 5
// 28.419 us; speedup vs baseline: 4.1298x; 2.3191x over previous
//
#include <hip/hip_runtime.h>
#include <math.h>

// Problem: x[B=32][N=2048][K=8], W[N][C=32][J=16][K=8], R[N][C]
// out[b][c][j] = squash_j( sum_n softmax_n(R)[n,c] * sum_k W[n,c,j,k]*x[b,n,k] )

#define NN 2048
#define CC 32

__device__ __forceinline__ void g2l16(const float* g, float* l) {
  __builtin_amdgcn_global_load_lds((const __attribute__((address_space(1))) void*)g,
                                   (__attribute__((address_space(3))) void*)l, 16, 0, 0);
}

// Kernel 1: fused softmax-stats + contraction.
// grid 512 = 64 chunks(32 n) x 8 c-quads; block 512 = 8 waves; 64KB LDS -> 2 blocks/CU,
// VGPR pinned to 128 budget via waves_per_eu(4,4). Wave ws does n = n0 + s*8 + ws, s<4.
// lane: j = lane&15, bo = lane>>4. Thread tile acc[ci 4][bi 8]; b = bo*8+bi, c = cq*4+ci.
// LDS: ldsW[2][4096]f (8-n W slabs; per n 128 granules, slot = g ^ (j>>1) swizzle,
//      inverse applied on staging source), ldsX[32][256]f ([n][k 8][b 32], reg-staged).
__global__ __launch_bounds__(512) __attribute__((amdgpu_waves_per_eu(4, 4)))
void caps_main(const float* __restrict__ x, const float* __restrict__ W,
               const float* __restrict__ R, float* __restrict__ P) {
  const int bid = blockIdx.x;
  const int cq = bid & 7;
  const int chunk = bid >> 3;
  const int n0 = chunk * 32;
  const int tid = threadIdx.x;
  const int ws = tid >> 6;
  const int lane = tid & 63;
  const int j = lane & 15;
  const int bo = lane >> 4;

  extern __shared__ float smem[];
  float* ldsW = smem;          // [2][4096] floats (32KB)
  float* ldsX = smem + 8192;   // [32][256] floats (32KB)
  float* red8 = smem + 4096;   // 32 floats inside slab1 (dead until s=0 prefetch)

  // ---- prologue: async-stage W slab 0 (16KB). LDS slot S <- source granule
  // g = S ^ (((S>>2)^(S>>4))&1) ^ (((S>>3)&1)<<1) ^ (((S>>4)&1)<<2)  [inverse of ^(j>>1)]
#pragma unroll
  for (int it = 0; it < 2; ++it) {
    int idx = it * 512 + tid;
    int nl = idx >> 7, S = idx & 127;
    int g = S ^ (((S >> 2) ^ (S >> 4)) & 1) ^ (((S >> 3) & 1) << 1) ^ (((S >> 4) & 1) << 2);
    g2l16(W + (size_t)(n0 + nl) * 4096 + cq * 512 + g * 4,
          ldsW + (size_t)(it * 512 + ws * 64) * 4);
  }

  // ---- reg-stage x into [n][k][b] (k<->b transpose; g2l16 can't) ----
  float4 xg[4];
  int xoff[4];
#pragma unroll
  for (int it = 0; it < 4; ++it) {
    int idx = it * 512 + tid;
    int nl = idx >> 6, r = idx & 63;
    int b = r & 31, kq = r >> 5;
    xg[it] = *(const float4*)(x + (size_t)b * (NN * 8) + (size_t)(n0 + nl) * 8 + kq * 4);
    xoff[it] = nl * 256 + kq * 128 + b;
  }
#pragma unroll
  for (int it = 0; it < 4; ++it) {
    float* d = ldsX + xoff[it];
    d[0] = xg[it].x; d[32] = xg[it].y; d[64] = xg[it].z; d[96] = xg[it].w;
  }

  // ---- phase 0 (overlaps staging): softmax denominators for this c-quad ----
  float se[4] = {0.f, 0.f, 0.f, 0.f};
#pragma unroll
  for (int i = 0; i < 4; ++i) {
    int n = i * 512 + tid;
    float4 a = *(const float4*)(R + (size_t)n * CC + cq * 4);
    se[0] += expf(a.x); se[1] += expf(a.y); se[2] += expf(a.z); se[3] += expf(a.w);
  }
#pragma unroll
  for (int ci = 0; ci < 4; ++ci) {
    float v = se[ci];
#pragma unroll
    for (int d = 32; d >= 1; d >>= 1) v += __shfl_xor(v, d, 64);
    se[ci] = v;
  }
  if (lane == 0) {
#pragma unroll
    for (int ci = 0; ci < 4; ++ci) red8[ws * 4 + ci] = se[ci];
  }
  __syncthreads();  // drains W slab0 g2l16 + x ds_writes too

  float inv4[4];
  {
    float t[4] = {0.f, 0.f, 0.f, 0.f};
#pragma unroll
    for (int w = 0; w < 8; ++w)
#pragma unroll
      for (int ci = 0; ci < 4; ++ci) t[ci] += red8[w * 4 + ci];
#pragma unroll
    for (int ci = 0; ci < 4; ++ci) inv4[ci] = 1.0f / t[ci];
  }
  __syncthreads();  // red8 consumed before slab-1 prefetch overwrites it

  float acc[4][8];
#pragma unroll
  for (int a = 0; a < 4; ++a)
#pragma unroll
    for (int b = 0; b < 8; ++b) acc[a][b] = 0.f;

  const int jsw = j >> 1;  // read-side W swizzle mask

#pragma unroll 1
  for (int s = 0; s < 4; ++s) {
    if (s < 3) {
      const int sb = n0 + (s + 1) * 8;
      float* wdst = ldsW + (size_t)((s + 1) & 1) * 4096;
#pragma unroll
      for (int it = 0; it < 2; ++it) {
        int idx = it * 512 + tid;
        int nl = idx >> 7, S = idx & 127;
        int g = S ^ (((S >> 2) ^ (S >> 4)) & 1) ^ (((S >> 3) & 1) << 1) ^ (((S >> 4) & 1) << 2);
        g2l16(W + (size_t)(sb + nl) * 4096 + cq * 512 + g * 4,
              wdst + (size_t)(it * 512 + ws * 64) * 4);
      }
    }
    const int n = n0 + s * 8 + ws;
    const float* Xn = ldsX + (size_t)(s * 8 + ws) * 256;
    const float* Wn = ldsW + (size_t)(s & 1) * 4096 + (size_t)ws * 512;

    const float* rr = R + (size_t)n * CC + cq * 4;  // wave-uniform
    float rv[4];
#pragma unroll
    for (int ci = 0; ci < 4; ++ci) rv[ci] = expf(rr[ci]) * inv4[ci];

#pragma unroll
    for (int kh = 0; kh < 2; ++kh) {
      // x columns for this k-half: [kk 4][bi 8] = 32 regs, conflict-free reads
      float4 xlo[4], xhi[4];
#pragma unroll
      for (int kk = 0; kk < 4; ++kk) {
        const float* xp = Xn + (kh * 4 + kk) * 32 + bo * 8;
        xlo[kk] = *(const float4*)xp;
        xhi[kk] = *(const float4*)(xp + 4);
      }
#pragma unroll
      for (int ci = 0; ci < 4; ++ci) {
        int slot = (ci * 32 + j * 2 + kh) ^ jsw;
        float4 wf = *(const float4*)(Wn + slot * 4);
        float rvv = rv[ci];
        float w0 = wf.x * rvv, w1 = wf.y * rvv, w2 = wf.z * rvv, w3 = wf.w * rvv;
        float a0, a1;
#pragma unroll
        for (int bi = 0; bi < 4; ++bi) {
          a0 = acc[ci][bi];
          a0 = fmaf(w0, (&xlo[0].x)[bi], a0);
          a0 = fmaf(w1, (&xlo[1].x)[bi], a0);
          a0 = fmaf(w2, (&xlo[2].x)[bi], a0);
          a0 = fmaf(w3, (&xlo[3].x)[bi], a0);
          acc[ci][bi] = a0;
          a1 = acc[ci][bi + 4];
          a1 = fmaf(w0, (&xhi[0].x)[bi], a1);
          a1 = fmaf(w1, (&xhi[1].x)[bi], a1);
          a1 = fmaf(w2, (&xhi[2].x)[bi], a1);
          a1 = fmaf(w3, (&xhi[3].x)[bi], a1);
          acc[ci][bi + 4] = a1;
        }
      }
    }
    __syncthreads();
  }

  // ---- cross-wave tree reduction (ldsW region dead: 4 regions x 2048 floats) ----
  float* red = smem;
#pragma unroll
  for (int half = 4; half >= 1; half >>= 1) {
    if (ws >= half && ws < 2 * half) {
      float* dst = red + (size_t)(ws - half) * 2048;
#pragma unroll
      for (int ci = 0; ci < 4; ++ci)
#pragma unroll
        for (int bi = 0; bi < 8; ++bi)
          dst[(ci * 8 + bi) * 64 + lane] = acc[ci][bi];
    }
    __syncthreads();
    if (ws < half) {
      const float* srcp = red + (size_t)ws * 2048;
#pragma unroll
      for (int ci = 0; ci < 4; ++ci)
#pragma unroll
        for (int bi = 0; bi < 8; ++bi)
          acc[ci][bi] += srcp[(ci * 8 + bi) * 64 + lane];
    }
    __syncthreads();
  }

  if (ws == 0) {
    float* dst = P + (size_t)bid * 2048;
#pragma unroll
    for (int ci = 0; ci < 4; ++ci)
#pragma unroll
      for (int bi = 0; bi < 8; ++bi)
        dst[(ci * 8 + bi) * 64 + lane] = acc[ci][bi];
  }
}

// Kernel 2: cross-chunk reduce + squash. 64 blocks x 256 threads.
__global__ void caps_reduce(const float* __restrict__ P, float* __restrict__ out) {
  const int g = blockIdx.x * 256 + threadIdx.x;  // b*512 + c*16 + j
  const int j = g & 15;
  const int c = (g >> 4) & 31;
  const int b = g >> 9;
  const int bo = b >> 3, bi = b & 7;
  const int cgi = c >> 2, ci = c & 3;
  const int idx = (ci * 8 + bi) * 64 + (bo * 16 + j);

  float s = 0.f;
#pragma unroll 16
  for (int ch = 0; ch < 64; ++ch) {
    s += P[(size_t)(ch * 8 + cgi) * 2048 + idx];
  }
  float sq = s * s;
  sq += __shfl_xor(sq, 8, 16);
  sq += __shfl_xor(sq, 4, 16);
  sq += __shfl_xor(sq, 2, 16);
  sq += __shfl_xor(sq, 1, 16);
  float ss = sq + 1e-7f;
  float scale = sqrtf(ss) / (1.0f + ss);
  out[g] = scale * s;
}

extern "C" void kernel_launch(void* const* d_in, const int* in_sizes, int n_in,
                              void* d_out, int out_size, void* d_ws, size_t ws_size,
                              hipStream_t stream) {
  const float* x = (const float*)d_in[0];   // 32*2048*8
  const float* W = (const float*)d_in[1];   // 2048*32*16*8
  const float* R = (const float*)d_in[2];   // 2048*32
  float* out = (float*)d_out;               // 32*32*16
  float* P = (float*)d_ws;                  // 512*2048 floats (4 MB)

  hipFuncSetAttribute((const void*)caps_main,
                      hipFuncAttributeMaxDynamicSharedMemorySize, 65536);

  caps_main<<<512, 512, 65536, stream>>>(x, W, R, P);
  caps_reduce<<<64, 256, 0, stream>>>(P, out);
}